// Round 1
// baseline (32.657 us; speedup 1.0000x reference)
//
#include <hip/hip_runtime.h>
#include <math.h>

#define K_CENTERS 512
#define T_TAB 4096
#define XMIN_T (-6.0f)
#define XMAX_T (6.0f)
#define H_TAB ((XMAX_T - XMIN_T) / (float)T_TAB)
#define INV_H ((float)T_TAB / (XMAX_T - XMIN_T))

// Kernel A: rank-sort the 512 centers by value (tie -> smaller original index).
// sC[rank] = value, oIdx[rank] = original index. O(K^2) comparisons, one block.
__global__ __launch_bounds__(512) void sort_centers_k(const float* __restrict__ centers,
                                                      float* __restrict__ sC,
                                                      int* __restrict__ oIdx) {
    __shared__ float c[K_CENTERS];
    int t = threadIdx.x;
    c[t] = centers[t];
    __syncthreads();
    float x = c[t];
    int rank = 0;
#pragma unroll 8
    for (int j = 0; j < K_CENTERS; ++j) {
        float cj = c[j];
        rank += (cj < x || (cj == x && j < t)) ? 1 : 0;
    }
    sC[rank] = x;
    oIdx[rank] = t;
}

// Kernel B: for each table node x_n = XMIN + n*h (n in [0..T_TAB]):
//   tabF[n]  = softout(x_n)  (full 512-center Gaussian softmax mean)
//   tabIns[n]= #{k : c_k < x_n}  (insertion point, order-independent count)
// 8 lanes per node, 64 centers each, LDS reduce.
__global__ __launch_bounds__(256) void build_table_k(const float* __restrict__ centers,
                                                     float* __restrict__ tabF,
                                                     int* __restrict__ tabIns) {
    __shared__ float rw[256], rwc[256];
    __shared__ int ri[256];
    int lid = threadIdx.x;
    int gid = blockIdx.x * 256 + lid;
    int n = gid >> 3;
    int s = gid & 7;
    float w = 0.f, wc = 0.f;
    int ic = 0;
    float xn = XMIN_T + (float)n * H_TAB;
    if (n <= T_TAB) {
        int k0 = s * 64;
#pragma unroll 8
        for (int q = 0; q < 64; ++q) {
            float cv = centers[k0 + q];
            float d = xn - cv;
            float e = __expf(-d * d);   // SIGMA = 1
            w += e;
            wc = fmaf(e, cv, wc);
            ic += (cv < xn) ? 1 : 0;
        }
    }
    rw[lid] = w; rwc[lid] = wc; ri[lid] = ic;
    __syncthreads();
    if ((lid & 7) == 0 && n <= T_TAB) {
        float W = 0.f, WC = 0.f;
        int I = 0;
        for (int q = 0; q < 8; ++q) { W += rw[lid + q]; WC += rwc[lid + q]; I += ri[lid + q]; }
        tabF[n] = WC / W;
        tabIns[n] = I;
    }
}

// Kernel C: per element: table-interp softout; exact f32-faithful argmin via
// candidate scan of value-sorted neighbors (replicates reference rounding +
// first-min tie-break); write zbar(=hardout), softout, hardout, symbols(float).
__global__ __launch_bounds__(256) void quant_main_k(const float* __restrict__ data,
                                                    const float* __restrict__ sC,
                                                    const int* __restrict__ oIdx,
                                                    const float* __restrict__ tabF,
                                                    const int* __restrict__ tabIns,
                                                    float* __restrict__ out, int N) {
    __shared__ float lsC[K_CENTERS];
    __shared__ int loI[K_CENTERS];
    int t = threadIdx.x;
    lsC[t] = sC[t];           lsC[t + 256] = sC[t + 256];
    loI[t] = oIdx[t];         loI[t + 256] = oIdx[t + 256];
    __syncthreads();

    int base = (blockIdx.x * 256 + t) * 4;
    if (base >= N) return;

    float4 xv = *reinterpret_cast<const float4*>(data + base);
    float xs[4] = {xv.x, xv.y, xv.z, xv.w};
    float zb[4], so[4], ho[4], sy[4];

#pragma unroll
    for (int e = 0; e < 4; ++e) {
        float x = xs[e];
        // ---- softout via table interpolation ----
        float u = (x - XMIN_T) * INV_H;
        int i0 = (int)floorf(u);
        i0 = min(max(i0, 0), T_TAB - 1);
        float frac = u - (float)i0;
        frac = fminf(fmaxf(frac, 0.f), 1.f);
        float f0 = tabF[i0];
        float f1 = tabF[i0 + 1];
        float soft = fmaf(frac, f1 - f0, f0);
        // ---- exact argmin: scan sorted candidates around insertion point ----
        int jlo = max(tabIns[i0] - 3, 0);
        int jhi = min(tabIns[i0 + 1] + 2, K_CENTERS - 1);
        float bd2 = 3.4e38f;
        int bidx = 1 << 30;
        float bc = 0.f;
        for (int j = jlo; j <= jhi; ++j) {
            float cv = lsC[j];
            float d = x - cv;       // same rounding as reference
            float d2 = d * d;       // same rounding as reference
            int oi = loI[j];
            bool better = (d2 < bd2) || ((d2 == bd2) && (oi < bidx));
            if (better) { bd2 = d2; bidx = oi; bc = cv; }
        }
        zb[e] = bc;                 // zbar forward value == hardout
        so[e] = soft;
        ho[e] = bc;
        sy[e] = (float)bidx;
    }

    *reinterpret_cast<float4*>(out + base)         = make_float4(zb[0], zb[1], zb[2], zb[3]);
    *reinterpret_cast<float4*>(out + N + base)     = make_float4(so[0], so[1], so[2], so[3]);
    *reinterpret_cast<float4*>(out + 2 * N + base) = make_float4(ho[0], ho[1], ho[2], ho[3]);
    *reinterpret_cast<float4*>(out + 3 * N + base) = make_float4(sy[0], sy[1], sy[2], sy[3]);
}

extern "C" void kernel_launch(void* const* d_in, const int* in_sizes, int n_in,
                              void* d_out, int out_size, void* d_ws, size_t ws_size,
                              hipStream_t stream) {
    const float* data    = (const float*)d_in[0];
    const float* centers = (const float*)d_in[1];
    float* out = (float*)d_out;
    int N = in_sizes[0];   // 524288

    // workspace layout (floats): [0,512) sortedC | [512,1024) origIdx |
    // [1024,1024+4104) tabF | [1024+4104, +4104) tabIns  (~37 KB total)
    float* ws   = (float*)d_ws;
    float* sC   = ws;
    int*   oIdx = (int*)(ws + 512);
    float* tabF = ws + 1024;
    int*   tabIns = (int*)(ws + 1024 + 4104);

    sort_centers_k<<<1, 512, 0, stream>>>(centers, sC, oIdx);

    int tabThreads = (T_TAB + 1) * 8;
    build_table_k<<<(tabThreads + 255) / 256, 256, 0, stream>>>(centers, tabF, tabIns);

    int mainThreads = N / 4;
    quant_main_k<<<(mainThreads + 255) / 256, 256, 0, stream>>>(data, sC, oIdx, tabF, tabIns, out, N);
}

// Round 2
// 16.389 us; speedup vs baseline: 1.9926x; 1.9926x over previous
//
#include <hip/hip_runtime.h>
#include <math.h>

#define K_CENTERS 512
#define T_TAB 8192
#define XMIN_T (-6.0f)
#define XMAX_T (6.0f)
#define H_TAB ((XMAX_T - XMIN_T) / (float)T_TAB)
#define INV_H ((float)T_TAB / (XMAX_T - XMIN_T))
#define SORT_BLOCKS 8
#define TAB_THREADS ((T_TAB + 1) * 8)
#define TAB_BLOCKS ((TAB_THREADS + 255) / 256)

// Fused setup dispatch.
// Blocks 0..7: rank-sort the 512 centers (tie -> smaller original index).
//   4 threads per center, 128 comparisons each, shfl_xor reduce.
//   pair[rank] = {value, (float)origIdx}
// Blocks 8..: softout/insertion table. 8 lanes per node, 64 centers each,
//   shfl_xor reduce within the 8 consecutive lanes.
//   tab[n] = {softout(x_n), (float)#{k: c_k < x_n}}
__global__ __launch_bounds__(256) void setup_k(const float* __restrict__ centers,
                                               float2* __restrict__ pair,
                                               float2* __restrict__ tab) {
    int t = threadIdx.x;
    int b = blockIdx.x;
    if (b < SORT_BLOCKS) {
        __shared__ float c[K_CENTERS];
        c[t] = centers[t];
        c[t + 256] = centers[t + 256];
        __syncthreads();
        int cidx = b * 64 + (t >> 2);
        int p = t & 3;
        float x = c[cidx];
        int rank = 0;
        int j0 = p * 128;
#pragma unroll 8
        for (int i = 0; i < 128; ++i) {
            int j = j0 + i;
            float cj = c[j];
            rank += (cj < x || (cj == x && j < cidx)) ? 1 : 0;
        }
        rank += __shfl_xor(rank, 1);
        rank += __shfl_xor(rank, 2);
        if (p == 0) pair[rank] = make_float2(x, (float)cidx);
    } else {
        int gid = (b - SORT_BLOCKS) * 256 + t;
        int n = gid >> 3;
        int s = gid & 7;
        if (n > T_TAB) return;
        float xn = XMIN_T + (float)n * H_TAB;
        float w = 0.f, wc = 0.f;
        int ic = 0;
        int k0 = s * 64;
#pragma unroll 8
        for (int q = 0; q < 64; ++q) {
            float cv = centers[k0 + q];
            float d = xn - cv;
            float e = __expf(-d * d);      // SIGMA = 1
            w += e;
            wc = fmaf(e, cv, wc);
            ic += (cv < xn) ? 1 : 0;
        }
        w  += __shfl_xor(w, 1);  wc += __shfl_xor(wc, 1);  ic += __shfl_xor(ic, 1);
        w  += __shfl_xor(w, 2);  wc += __shfl_xor(wc, 2);  ic += __shfl_xor(ic, 2);
        w  += __shfl_xor(w, 4);  wc += __shfl_xor(wc, 4);  ic += __shfl_xor(ic, 4);
        if (s == 0) tab[n] = make_float2(wc / w, (float)ic);
    }
}

// Main kernel: per element: table-interp softout; exact f32-faithful argmin via
// candidate scan of value-sorted neighbors (replicates reference d=x-c, d2=d*d
// rounding and first-min (smallest original index) tie-break).
// Outputs (concat): zbar(=hardout), softout, hardout, symbols(as float).
__global__ __launch_bounds__(256) void quant_main_k(const float* __restrict__ data,
                                                    const float2* __restrict__ pair,
                                                    const float2* __restrict__ tab,
                                                    float* __restrict__ out, int N) {
    __shared__ float2 lsP[K_CENTERS];
    int t = threadIdx.x;
    lsP[t] = pair[t];
    lsP[t + 256] = pair[t + 256];
    __syncthreads();

    int base = (blockIdx.x * 256 + t) * 4;
    if (base >= N) return;

    float4 xv = *reinterpret_cast<const float4*>(data + base);
    float xs[4] = {xv.x, xv.y, xv.z, xv.w};
    float zb[4], so[4], sy[4];

#pragma unroll
    for (int e = 0; e < 4; ++e) {
        float x = xs[e];
        // ---- softout via table interpolation ----
        float u = (x - XMIN_T) * INV_H;
        int i0 = (int)floorf(u);
        i0 = min(max(i0, 0), T_TAB - 1);
        float frac = u - (float)i0;
        frac = fminf(fmaxf(frac, 0.f), 1.f);
        float2 r0 = tab[i0];
        float2 r1 = tab[i0 + 1];
        so[e] = fmaf(frac, r1.x - r0.x, r0.x);
        // ---- exact argmin: scan sorted candidates around insertion point ----
        int jlo = max((int)r0.y - 3, 0);
        int jhi = min((int)r1.y + 2, K_CENTERS - 1);
        float bd2 = 3.4e38f;
        float bfo = 1.0e9f;   // original index as float (exact for <512)
        float bc = 0.f;
        for (int j = jlo; j <= jhi; ++j) {
            float2 P = lsP[j];
            float d = x - P.x;      // same rounding as reference
            float d2 = d * d;       // same rounding as reference
            bool better = (d2 < bd2) || ((d2 == bd2) && (P.y < bfo));
            if (better) { bd2 = d2; bfo = P.y; bc = P.x; }
        }
        zb[e] = bc;                 // zbar forward value == hardout
        sy[e] = bfo;
    }

    *reinterpret_cast<float4*>(out + base)         = make_float4(zb[0], zb[1], zb[2], zb[3]);
    *reinterpret_cast<float4*>(out + N + base)     = make_float4(so[0], so[1], so[2], so[3]);
    *reinterpret_cast<float4*>(out + 2 * N + base) = make_float4(zb[0], zb[1], zb[2], zb[3]);
    *reinterpret_cast<float4*>(out + 3 * N + base) = make_float4(sy[0], sy[1], sy[2], sy[3]);
}

extern "C" void kernel_launch(void* const* d_in, const int* in_sizes, int n_in,
                              void* d_out, int out_size, void* d_ws, size_t ws_size,
                              hipStream_t stream) {
    const float* data    = (const float*)d_in[0];
    const float* centers = (const float*)d_in[1];
    float* out = (float*)d_out;
    int N = in_sizes[0];   // 524288

    // ws layout (float2): [0,512) sorted {value, origIdx} | [512, 512+8193) table
    float2* pair = (float2*)d_ws;
    float2* tab  = pair + K_CENTERS;

    setup_k<<<SORT_BLOCKS + TAB_BLOCKS, 256, 0, stream>>>(centers, pair, tab);

    int mainThreads = N / 4;
    quant_main_k<<<(mainThreads + 255) / 256, 256, 0, stream>>>(data, pair, tab, out, N);
}